// Round 4
// baseline (89.596 us; speedup 1.0000x reference)
//
#include <hip/hip_runtime.h>
#include <math.h>

// Problem constants (fixed by the reference)
#define HOPS 2
#define BATCH 2048
#define MEM 64
#define DIM 16
#define NREL 32
#define RSTRIDE 20   // padded LDS row stride (floats): keeps float4 alignment,
                     // spreads random-ridx b128 reads across bank groups.

// One 256-thread block (4 waves) per batch element b.
//   slot = tid>>1 in [0,128): h = slot>>6, m = slot&63
//   sub  = tid&1 : which 8-float half of the 16-dim row this lane owns.
// Geometry rationale (R3): vs the 512-thread version this doubles resident
// blocks per CU (8 vs 4) and doubles per-lane outstanding gathers (4 vs 2),
// targeting the random-64B-gather throughput that bounds this kernel, while
// keeping TA coalescing (2 lanes share each row's two 16-B segments).
// Algebra:
//   logit = item . (R @ head) = (item . R) . head; N_REL=32 so itemR[32][16]
//   is precomputed per block into LDS (2 entries/thread).
//   predicts[b] = sigmoid( sum_h (sum_m e_m*(tail_m.item)) / (sum_m e_m) )
//   No stable-softmax max pass: |logit| <~ 0.5 (0.1-scale normal inputs),
//   softmax is shift-invariant; exp cannot overflow.
__global__ __launch_bounds__(256)
void ripple_kernel(const int* __restrict__ items,
                   const int* __restrict__ heads,
                   const int* __restrict__ relations,
                   const int* __restrict__ tails,
                   const float* __restrict__ ent_emb,
                   const float* __restrict__ rel_emb,
                   float* __restrict__ out)
{
    const int b    = blockIdx.x;
    const int tid  = threadIdx.x;
    const int sub  = tid & 1;      // 8-float half: 0 or 1
    const int slot = tid >> 1;     // 0..127
    const int h    = slot >> 6;    // hop
    const int m    = slot & 63;    // memory index
    const int wave = tid >> 6;     // 0..3 (waves 0-1: h=0, waves 2-3: h=1)

    __shared__ float s_itemR[NREL * RSTRIDE];  // 2.5 KB
    __shared__ float s_num[4];
    __shared__ float s_den[4];

    // ---- per-slot indices (2 lanes share one address -> HW broadcast) ----
    const int base = h * (BATCH * MEM) + b * MEM + m;
    const int hidx = heads[base];
    const int ridx = relations[base];
    const int tidx = tails[base];

    // ---- item embedding: block-uniform address -> broadcast into regs ----
    const float4* ip = (const float4*)(ent_emb + (size_t)items[b] * DIM);
    const float4 it0 = ip[0], it1 = ip[1], it2 = ip[2], it3 = ip[3];

    // ---- issue all 4 gathers NOW (latency overlaps itemR compute) ----
    const float4* hp = (const float4*)(ent_emb + (size_t)hidx * DIM + sub * 8);
    const float4* tp = (const float4*)(ent_emb + (size_t)tidx * DIM + sub * 8);
    const float4 hA = hp[0], hB = hp[1];
    const float4 tA = tp[0], tB = tp[1];

    // ---- itemR[r][j] = sum_i item[i]*R[r][i][j]; 2 entries per thread ----
    #pragma unroll
    for (int ent = 0; ent < 2; ++ent) {
        const int e_id = tid + ent * 256;      // 0..511
        const int r = e_id >> 4;               // 0..31
        const int j = e_id & 15;               // 0..15
        const float* Rp = rel_emb + r * (DIM * DIM) + j;  // column j, stride 16
        float acc;
        acc = it0.x * Rp[0];
        acc = fmaf(it0.y, Rp[16],  acc);
        acc = fmaf(it0.z, Rp[32],  acc);
        acc = fmaf(it0.w, Rp[48],  acc);
        acc = fmaf(it1.x, Rp[64],  acc);
        acc = fmaf(it1.y, Rp[80],  acc);
        acc = fmaf(it1.z, Rp[96],  acc);
        acc = fmaf(it1.w, Rp[112], acc);
        acc = fmaf(it2.x, Rp[128], acc);
        acc = fmaf(it2.y, Rp[144], acc);
        acc = fmaf(it2.z, Rp[160], acc);
        acc = fmaf(it2.w, Rp[176], acc);
        acc = fmaf(it3.x, Rp[192], acc);
        acc = fmaf(it3.y, Rp[208], acc);
        acc = fmaf(it3.z, Rp[224], acc);
        acc = fmaf(it3.w, Rp[240], acc);
        s_itemR[r * RSTRIDE + j] = acc;
    }
    __syncthreads();

    // ---- per-lane partial dots over this lane's 8-float half ----
    const float4* irp = (const float4*)(s_itemR + ridx * RSTRIDE + sub * 8);
    const float4 irA = irp[0], irB = irp[1];
    const float4 iA  = sub ? it2 : it0;
    const float4 iB  = sub ? it3 : it1;

    float lpart = hA.x*irA.x + hA.y*irA.y + hA.z*irA.z + hA.w*irA.w
                + hB.x*irB.x + hB.y*irB.y + hB.z*irB.z + hB.w*irB.w;
    float tpart = tA.x*iA.x  + tA.y*iA.y  + tA.z*iA.z  + tA.w*iA.w
                + tB.x*iB.x  + tB.y*iB.y  + tB.z*iB.z  + tB.w*iB.w;

    // logit for this slot: reduce over the 2 sub-lanes
    lpart += __shfl_xor(lpart, 1, 64);

    // ---- unnormalized softmax weight; fold tail dot directly in ----
    const float e = __expf(lpart);
    float num = e * tpart;   // wave-sums to sum_m e_m * (tail_m . item)
    float den = e * 0.5f;    // wave-sums to sum_m e_m (2 dup lanes/slot)
    #pragma unroll
    for (int off = 1; off < 64; off <<= 1) {
        num += __shfl_xor(num, off, 64);
        den += __shfl_xor(den, off, 64);
    }
    if ((tid & 63) == 0) { s_num[wave] = num; s_den[wave] = den; }
    __syncthreads();

    if (tid == 0) {
        const float x = (s_num[0] + s_num[1]) / (s_den[0] + s_den[1])
                      + (s_num[2] + s_num[3]) / (s_den[2] + s_den[3]);
        out[b] = 1.0f / (1.0f + __expf(-x));
    }
}

extern "C" void kernel_launch(void* const* d_in, const int* in_sizes, int n_in,
                              void* d_out, int out_size, void* d_ws, size_t ws_size,
                              hipStream_t stream) {
    const int*   items     = (const int*)d_in[0];
    const int*   heads     = (const int*)d_in[1];
    const int*   relations = (const int*)d_in[2];
    const int*   tails     = (const int*)d_in[3];
    const float* ent_emb   = (const float*)d_in[4];
    const float* rel_emb   = (const float*)d_in[5];
    float*       out       = (float*)d_out;

    ripple_kernel<<<BATCH, 256, 0, stream>>>(items, heads, relations, tails,
                                             ent_emb, rel_emb, out);
}

// Round 5
// 89.596 us; speedup vs baseline: 1.0000x; 1.0000x over previous
//
#include <hip/hip_runtime.h>
#include <math.h>

// Problem constants (fixed by the reference)
#define HOPS 2
#define BATCH 2048
#define MEM 64
#define DIM 16
#define NREL 32
#define BPB 4        // batch elements per block: amortizes the 32 KB rel_emb
                     // read (512 L1 line-misses) across 4 items -> per-item
                     // L1 miss count drops ~2x (the R4 theory).

// One 512-thread block per 4 batch elements.
//   thread t -> slot: bl = t>>7 (item in block), h = (t>>6)&1, m = t&63.
//   wave w = t>>6 == 2*bl + h  => softmax over m is EXACTLY one wave.
// Each thread owns the full 16-float row of its (head, tail) entities.
// Algebra:
//   logit = item . (R @ head) = (item . R) . head; N_REL=32 so itemR[bl][32][16]
//   is precomputed once per block: each thread owns one (r,j) column and
//   accumulates it for all 4 items, reading rel_emb exactly ONCE per block.
//   predicts[b] = sigmoid( sum_h (sum_m e_m*(tail_m.item)) / (sum_m e_m) )
//   No stable-softmax max pass: |logit| <~ 0.5 (0.1-scale normal inputs),
//   softmax is shift-invariant; exp cannot overflow.
__global__ __launch_bounds__(512)
void ripple_kernel(const int* __restrict__ items,
                   const int* __restrict__ heads,
                   const int* __restrict__ relations,
                   const int* __restrict__ tails,
                   const float* __restrict__ ent_emb,
                   const float* __restrict__ rel_emb,
                   float* __restrict__ out)
{
    const int tid  = threadIdx.x;
    const int b0   = blockIdx.x * BPB;
    const int bl   = tid >> 7;        // 0..3 item-in-block
    const int h    = (tid >> 6) & 1;  // hop
    const int m    = tid & 63;        // memory index == lane
    const int wave = tid >> 6;        // 0..7 == 2*bl + h
    const int b    = b0 + bl;

    __shared__ float s_item[BPB][DIM];           // 256 B
    __shared__ float s_itemR[BPB][NREL][DIM];    // 8 KB
    __shared__ float s_num[2 * BPB];
    __shared__ float s_den[2 * BPB];

    // ---- per-slot indices (coalesced: lanes = consecutive m) ----
    const int base = h * (BATCH * MEM) + b * MEM + m;
    const int hidx = heads[base];
    const int ridx = relations[base];
    const int tidx = tails[base];

    // ---- issue head/tail row gathers NOW (full 64-B row per lane);
    //      latency overlaps the itemR precompute ----
    const float4* hp = (const float4*)(ent_emb + (size_t)hidx * DIM);
    const float4* tp = (const float4*)(ent_emb + (size_t)tidx * DIM);
    const float4 h0 = hp[0], h1 = hp[1], h2 = hp[2], h3 = hp[3];
    const float4 t0 = tp[0], t1 = tp[1], t2 = tp[2], t3 = tp[3];

    // ---- item rows -> LDS (16 threads, one float4 each) ----
    if (tid < 4 * BPB) {
        const int ib  = tid >> 2;
        const int seg = tid & 3;
        ((float4*)s_item[ib])[seg] =
            ((const float4*)(ent_emb + (size_t)items[b0 + ib] * DIM))[seg];
    }
    __syncthreads();

    // ---- itemR[q][r][j] = sum_i item_q[i] * R[r][i][j] ----
    // thread owns column (r = tid>>4, j = tid&15): reads rel_emb element
    // once, FMAs into all BPB item accumulators (rel_emb read 1x per block).
    {
        const int r = tid >> 4;    // 0..31
        const int j = tid & 15;    // 0..15
        const float* Rp = rel_emb + r * (DIM * DIM) + j;  // stride DIM
        float acc0 = 0.f, acc1 = 0.f, acc2 = 0.f, acc3 = 0.f;
        #pragma unroll
        for (int i = 0; i < DIM; ++i) {
            const float v = Rp[i * DIM];
            acc0 = fmaf(s_item[0][i], v, acc0);
            acc1 = fmaf(s_item[1][i], v, acc1);
            acc2 = fmaf(s_item[2][i], v, acc2);
            acc3 = fmaf(s_item[3][i], v, acc3);
        }
        s_itemR[0][r][j] = acc0;
        s_itemR[1][r][j] = acc1;
        s_itemR[2][r][j] = acc2;
        s_itemR[3][r][j] = acc3;
    }
    __syncthreads();

    // ---- full in-lane dots: logit = itemR[bl][ridx] . head,
    //                         tdot  = tail . item[bl] ----
    const float4* irp = (const float4*)s_itemR[bl][ridx];
    const float4 r0 = irp[0], r1 = irp[1], r2 = irp[2], r3 = irp[3];
    const float4* ipl = (const float4*)s_item[bl];
    const float4 i0 = ipl[0], i1 = ipl[1], i2 = ipl[2], i3 = ipl[3];

    float logit = h0.x*r0.x + h0.y*r0.y + h0.z*r0.z + h0.w*r0.w
                + h1.x*r1.x + h1.y*r1.y + h1.z*r1.z + h1.w*r1.w
                + h2.x*r2.x + h2.y*r2.y + h2.z*r2.z + h2.w*r2.w
                + h3.x*r3.x + h3.y*r3.y + h3.z*r3.z + h3.w*r3.w;
    float tdot  = t0.x*i0.x + t0.y*i0.y + t0.z*i0.z + t0.w*i0.w
                + t1.x*i1.x + t1.y*i1.y + t1.z*i1.z + t1.w*i1.w
                + t2.x*i2.x + t2.y*i2.y + t2.z*i2.z + t2.w*i2.w
                + t3.x*i3.x + t3.y*i3.y + t3.z*i3.z + t3.w*i3.w;

    // ---- unnormalized softmax over this wave's 64 m-slots ----
    const float e = __expf(logit);
    float num = e * tdot;
    float den = e;
    #pragma unroll
    for (int off = 1; off < 64; off <<= 1) {
        num += __shfl_xor(num, off, 64);
        den += __shfl_xor(den, off, 64);
    }
    if (m == 0) { s_num[wave] = num; s_den[wave] = den; }
    __syncthreads();

    // ---- combine hops, sigmoid, write (4 outputs per block) ----
    if (tid < BPB) {
        const float x = s_num[2*tid]     / s_den[2*tid]
                      + s_num[2*tid + 1] / s_den[2*tid + 1];
        out[b0 + tid] = 1.0f / (1.0f + __expf(-x));
    }
}

extern "C" void kernel_launch(void* const* d_in, const int* in_sizes, int n_in,
                              void* d_out, int out_size, void* d_ws, size_t ws_size,
                              hipStream_t stream) {
    const int*   items     = (const int*)d_in[0];
    const int*   heads     = (const int*)d_in[1];
    const int*   relations = (const int*)d_in[2];
    const int*   tails     = (const int*)d_in[3];
    const float* ent_emb   = (const float*)d_in[4];
    const float* rel_emb   = (const float*)d_in[5];
    float*       out       = (float*)d_out;

    ripple_kernel<<<BATCH / BPB, 512, 0, stream>>>(items, heads, relations,
                                                   tails, ent_emb, rel_emb, out);
}